// Round 2
// baseline (1218.477 us; speedup 1.0000x reference)
//
#include <hip/hip_runtime.h>
#include <stdint.h>

#define PI_F      3.14159265358979323846f
#define TWO_PI_F  6.28318530717958647692f
#define DT_F      0.05f
#define DIFF_SCALE_F 0.3f

typedef short short8 __attribute__((ext_vector_type(8)));
typedef float f32x4 __attribute__((ext_vector_type(4)));
typedef int   i32x4 __attribute__((ext_vector_type(4)));
typedef unsigned int u32x4 __attribute__((ext_vector_type(4)));
typedef unsigned int u32x2 __attribute__((ext_vector_type(2)));

__device__ __forceinline__ unsigned short f2bf(float x) {
    unsigned int u = __float_as_uint(x);
    u += 0x7FFFu + ((u >> 16) & 1u);
    return (unsigned short)(u >> 16);
}
__device__ __forceinline__ float bf2f(unsigned short h) {
    return __uint_as_float(((unsigned int)h) << 16);
}
__device__ __forceinline__ float sigf(float x) {
    return 1.0f / (1.0f + __expf(-x));
}
__device__ __forceinline__ float tanhfast(float x) {
    return 1.0f - 2.0f / (1.0f + __expf(2.0f * x));
}
__device__ __forceinline__ float siluf(float x) {
    return x / (1.0f + __expf(-x));
}
__device__ __forceinline__ float wrapf(float t) {
    float w = fmodf(t + PI_F, TWO_PI_F);
    w = (w < 0.0f) ? w + TWO_PI_F : w;
    return w - PI_F;
}
__device__ __forceinline__ float dot4(const float* __restrict__ W, const float* __restrict__ X, int K) {
    float a = 0.0f;
#pragma unroll 4
    for (int kk = 0; kk < K; kk += 4) {
        f32x4 wv = *(const f32x4*)(W + kk);
        f32x4 xv = *(const f32x4*)(X + kk);
        a += wv[0]*xv[0] + wv[1]*xv[1] + wv[2]*xv[2] + wv[3]*xv[3];
    }
    return a;
}

// ---------------- K0: convert GRU weights to bf16 ----------------
__global__ void prep_kernel(const float* __restrict__ wih, const float* __restrict__ whh,
                            unsigned short* __restrict__ wihb, unsigned short* __restrict__ whhb) {
    int i = blockIdx.x * 256 + threadIdx.x;
    if (i < 384*512) wihb[i] = f2bf(wih[i]);
    if (i < 384*128) whhb[i] = f2bf(whh[i]);
}

// ---------------- K1: gi = [sin|cos](context) @ wih^T  (bf16 MFMA) ----------------
// Output layout (elements, bf16): gi[((t*256 + bg)*4 + w)*384 + (hf*3+g)*64 + jl*4 + b&3]
//   where b = batch (bg = b>>2), j = w*32 + hf*16 + jl is the per-gate hidden col, g = gate.
__launch_bounds__(512)
__global__ void gi_gemm_kernel(const float* __restrict__ ctx_ang,
                               const unsigned short* __restrict__ wihb,
                               unsigned short* __restrict__ gi) {
    __shared__ __align__(16) unsigned short As[2][128*64];  // [sin/cos][row][64 k], 16B-granule swizzled

    const int tid = threadIdx.x;
    const int lane = tid & 63;
    const int w  = tid >> 6;     // 0..7
    const int wm = w >> 2;       // 0..1 (M half)
    const int wn = w & 3;        // 0..3 (N quarter: 96 cols)
    const int l15 = lane & 15;
    const int l4  = lane >> 4;
    const int mt = blockIdx.x;   // 0..2047
    const int t  = mt >> 3;
    const int b0 = (mt & 7) * 128;

    const int srow = tid >> 2;   // 0..127 staging row
    const int q    = tid & 3;    // quarter of 64 d-values

    f32x4 acc[4][6];
    const f32x4 z4 = {0.0f, 0.0f, 0.0f, 0.0f};
#pragma unroll
    for (int mi = 0; mi < 4; ++mi)
#pragma unroll
        for (int ns = 0; ns < 6; ++ns) acc[mi][ns] = z4;

    for (int dt = 0; dt < 4; ++dt) {
        // --- load 16 context values, compute sin+cos, pack bf16 (in regs) ---
        float v[16];
        {
            const float* src = ctx_ang + ((size_t)(b0 + srow) * 256 + t) * 256 + dt*64 + q*16;
#pragma unroll
            for (int j = 0; j < 4; ++j) {
                f32x4 x = *(const f32x4*)(src + j*4);
#pragma unroll
                for (int i = 0; i < 4; ++i) v[j*4+i] = x[i];
            }
        }
        unsigned int us[8], uc[8];
#pragma unroll
        for (int p = 0; p < 8; ++p) {
            float a0 = v[2*p], a1 = v[2*p+1];
            us[p] = (unsigned int)f2bf(__sinf(a0)) | ((unsigned int)f2bf(__sinf(a1)) << 16);
            uc[p] = (unsigned int)f2bf(__cosf(a0)) | ((unsigned int)f2bf(__cosf(a1)) << 16);
        }
        __syncthreads();   // previous iteration's fragment reads complete
#pragma unroll
        for (int gg = 0; gg < 2; ++gg) {
            int g  = q*2 + gg;
            int gs = g ^ (srow & 7);
            u32x4 ws = { us[gg*4+0], us[gg*4+1], us[gg*4+2], us[gg*4+3] };
            u32x4 wc = { uc[gg*4+0], uc[gg*4+1], uc[gg*4+2], uc[gg*4+3] };
            *(u32x4*)((char*)&As[0][0] + srow*128 + gs*16) = ws;
            *(u32x4*)((char*)&As[1][0] + srow*128 + gs*16) = wc;
        }
        __syncthreads();

        // --- MFMA over both halves (sin -> k base dt*64, cos -> 256 + dt*64) ---
#pragma unroll
        for (int half = 0; half < 2; ++half) {
            const char* Ab = (const char*)&As[half][0];
            const int kbase = half*256 + dt*64;
#pragma unroll
            for (int ki = 0; ki < 2; ++ki) {
                short8 aF[4], bF[6];
#pragma unroll
                for (int mi = 0; mi < 4; ++mi) {
                    int row = wm*64 + mi*16 + l15;
                    int kg  = ki*4 + l4;
                    aF[mi] = *(const short8*)(Ab + row*128 + ((kg ^ (row & 7)))*16);
                }
#pragma unroll
                for (int ns = 0; ns < 6; ++ns) {
                    int col = wn*96 + ns*16 + l15;
                    bF[ns] = *(const short8*)(wihb + (size_t)col*512 + kbase + ki*32 + l4*8);
                }
#pragma unroll
                for (int mi = 0; mi < 4; ++mi)
#pragma unroll
                    for (int ns = 0; ns < 6; ++ns)
                        acc[mi][ns] = __builtin_amdgcn_mfma_f32_16x16x32_bf16(aF[mi], bF[ns], acc[mi][ns], 0, 0, 0);
            }
        }
    }

    // --- epilogue: write gi (re-blocked layout, 8B packed stores) ---
#pragma unroll
    for (int mi = 0; mi < 4; ++mi) {
        int bl = wm*64 + mi*16 + l4*4;       // local batch base for r=0 (multiple of 4)
        int bg = (b0 + bl) >> 2;
#pragma unroll
        for (int ns = 0; ns < 6; ++ns) {
            int col = wn*96 + ns*16 + l15;   // 0..383
            int g  = col >> 7;
            int j  = col & 127;
            int wv = j >> 5, hf = (j >> 4) & 1, jl = j & 15;
            size_t e = (((size_t)t*256 + bg)*4 + wv)*384 + (size_t)((hf*3 + g)*64 + jl*4);
            unsigned int lo = (unsigned int)f2bf(acc[mi][ns][0]) | ((unsigned int)f2bf(acc[mi][ns][1]) << 16);
            unsigned int hi = (unsigned int)f2bf(acc[mi][ns][2]) | ((unsigned int)f2bf(acc[mi][ns][3]) << 16);
            u32x2 pk = { lo, hi };
            *(u32x2*)(gi + e) = pk;
        }
    }
}

// ---------------- K2: GRU scan + proj + SDE (4 batch rows per block) ----------------

#define SYNC_RAW() do { \
    asm volatile("s_waitcnt lgkmcnt(0)" ::: "memory"); \
    __builtin_amdgcn_s_barrier(); \
    __builtin_amdgcn_sched_barrier(0); \
} while (0)

#define LOADPF(PF, tt) do { \
    if (l4 == 0) { \
        const unsigned short* _p = gbase + (size_t)(tt)*393216; \
        _Pragma("unroll") \
        for (int _q = 0; _q < 6; ++_q) PF[_q] = *(const u32x2*)(_p + _q*64 + l15*4); \
    } \
} while (0)

#define STEP(RDBUF, WRBUF, PF) do { \
    short8 aF[4]; \
    _Pragma("unroll") \
    for (int kt = 0; kt < 4; ++kt) \
        aF[kt] = *(const short8*)((const char*)(RDBUF) + l15*256 + (((kt*4 + l4) ^ (l15 & 7)))*16); \
    f32x4 acc[6]; \
    _Pragma("unroll") \
    for (int g2 = 0; g2 < 6; ++g2) acc[g2] = z4; \
    _Pragma("unroll") \
    for (int kt = 0; kt < 4; ++kt) { \
        acc[0] = __builtin_amdgcn_mfma_f32_16x16x32_bf16(aF[kt], whB[0][kt], acc[0], 0, 0, 0); \
        acc[2] = __builtin_amdgcn_mfma_f32_16x16x32_bf16(aF[kt], whB[2][kt], acc[2], 0, 0, 0); \
        acc[4] = __builtin_amdgcn_mfma_f32_16x16x32_bf16(aF[kt], whB[4][kt], acc[4], 0, 0, 0); \
    } \
    _Pragma("unroll") \
    for (int kt = 0; kt < 4; ++kt) { \
        acc[1] = __builtin_amdgcn_mfma_f32_16x16x32_bf16(aF[kt], whB[1][kt], acc[1], 0, 0, 0); \
        acc[3] = __builtin_amdgcn_mfma_f32_16x16x32_bf16(aF[kt], whB[3][kt], acc[3], 0, 0, 0); \
        acc[5] = __builtin_amdgcn_mfma_f32_16x16x32_bf16(aF[kt], whB[5][kt], acc[5], 0, 0, 0); \
    } \
    _Pragma("unroll") \
    for (int hf = 0; hf < 2; ++hf) { \
        const f32x4 aR = acc[hf], aZ = acc[2 + hf], aN = acc[4 + hf]; \
        const u32x2 pR = PF[hf*3 + 0], pZ = PF[hf*3 + 1], pN = PF[hf*3 + 2]; \
        _Pragma("unroll") \
        for (int r = 0; r < 4; ++r) { \
            unsigned int uR = (r < 2) ? pR[0] : pR[1]; \
            unsigned int uZ = (r < 2) ? pZ[0] : pZ[1]; \
            unsigned int uN = (r < 2) ? pN[0] : pN[1]; \
            const int sh = (r & 1) * 16; \
            float ir  = bf2f((unsigned short)(uR >> sh)) + bR[hf]; \
            float iz  = bf2f((unsigned short)(uZ >> sh)) + bZ[hf]; \
            float in_ = bf2f((unsigned short)(uN >> sh)) + bN[hf]; \
            float rg = sigf(ir + aR[r]); \
            float zg = sigf(iz + aZ[r]); \
            float ng = tanhfast(in_ + rg * (aN[r] + bBN[hf])); \
            float hnew = ng + zg * (H[hf][r] - ng); \
            H[hf][r] = hnew; \
            if (l4 == 0) { \
                int gn = (w*4 + hf*2 + (l15 >> 3)) ^ r; \
                *(unsigned short*)((char*)(WRBUF) + r*256 + gn*16 + (l15 & 7)*2) = f2bf(hnew); \
            } \
        } \
    } \
} while (0)

__launch_bounds__(256, 1)
__global__ void scan_sde_kernel(const float* __restrict__ ctx_ang,
                                const float* __restrict__ dW,
                                const unsigned short* __restrict__ whhb,
                                const float* __restrict__ gru_b,
                                const float* __restrict__ gru_bn,
                                const float* __restrict__ proj_w,
                                const float* __restrict__ proj_b,
                                const float* __restrict__ dr_w0, const float* __restrict__ dr_b0,
                                const float* __restrict__ dr_w1, const float* __restrict__ dr_b1,
                                const float* __restrict__ dr_w2, const float* __restrict__ dr_b2,
                                const float* __restrict__ dr_w3, const float* __restrict__ dr_b3,
                                const float* __restrict__ df_w0, const float* __restrict__ df_b0,
                                const float* __restrict__ df_w1, const float* __restrict__ df_b1,
                                const float* __restrict__ df_w2, const float* __restrict__ df_b2,
                                const unsigned short* __restrict__ gi,
                                float* __restrict__ out) {
    __shared__ __align__(16) unsigned short hAbuf[2][16*128];  // bf16 h tiles (rows 0..3 valid), swizzled
    __shared__ __align__(16) float h32[4*128];
    __shared__ __align__(16) float th[4*256];
    __shared__ __align__(16) float ctxs[4*64];
    __shared__ __align__(16) float inp[4*576];
    __shared__ __align__(16) float hb1[4*128];
    __shared__ __align__(16) float hb2[4*128];
    __shared__ __align__(16) float mus[4*256];

    const int tid  = threadIdx.x;
    const int lane = tid & 63;
    const int w    = tid >> 6;        // wave 0..3
    const int l15  = lane & 15;
    const int l4   = lane >> 4;
    const int bg   = blockIdx.x;
    const int b0   = bg * 4;          // batch rows b0..b0+3

    // --- zero both hA buffers (rows 4..15 stay zero forever) ---
    {
        u32x4 z = {0u,0u,0u,0u};
        *(u32x4*)((char*)&hAbuf[0][0] + tid*16) = z;
        *(u32x4*)((char*)&hAbuf[1][0] + tid*16) = z;
    }

    // --- whh fragments in registers: wave w handles cols {w*32..w*32+32} of each gate ---
    short8 whB[6][4];
#pragma unroll
    for (int g2 = 0; g2 < 6; ++g2) {
        int g = g2 >> 1, hf = g2 & 1;
        int j = g*128 + w*32 + hf*16 + l15;
#pragma unroll
        for (int kt = 0; kt < 4; ++kt)
            whB[g2][kt] = *(const short8*)(whhb + (size_t)j*128 + kt*32 + l4*8);
    }

    // --- per-lane biases (valid content needed only for l4==0) ---
    float bR[2], bZ[2], bN[2], bBN[2];
#pragma unroll
    for (int hf = 0; hf < 2; ++hf) {
        int jj = w*32 + hf*16 + l15;
        bR[hf]  = gru_b[jj];
        bZ[hf]  = gru_b[128 + jj];
        bN[hf]  = gru_b[256 + jj];
        bBN[hf] = gru_bn[jj];
    }
    float H[2][4] = {{0.f,0.f,0.f,0.f},{0.f,0.f,0.f,0.f}};
    const f32x4 z4 = {0.0f,0.0f,0.0f,0.0f};

    // --- gi register prefetch, 2 steps deep ---
    const unsigned short* gbase = gi + ((size_t)bg*4 + w) * 384;
    u32x2 PFa[6], PFb[6];
    LOADPF(PFa, 0);
    LOADPF(PFb, 1);
    __syncthreads();   // hA zeros visible

    // ==== GRU scan over T=256 (1 raw barrier per step, double-buffered hA) ====
    for (int t = 0; t < 256; t += 2) {
        STEP(&hAbuf[0][0], &hAbuf[1][0], PFa);
        if (t + 2 < 256) LOADPF(PFa, t + 2);
        SYNC_RAW();
        STEP(&hAbuf[1][0], &hAbuf[0][0], PFb);
        if (t + 3 < 256) LOADPF(PFb, t + 3);
        SYNC_RAW();
    }

    // --- final h (fp32, in regs) -> LDS for projection ---
    if (l4 == 0) {
#pragma unroll
        for (int hf = 0; hf < 2; ++hf)
#pragma unroll
            for (int r = 0; r < 4; ++r)
                h32[r*128 + w*32 + hf*16 + l15] = H[hf][r];
    }
    __syncthreads();

    // ==== ctx = h_final @ proj_w^T + proj_b ====
    {
        int b = tid >> 6, c = tid & 63;
        ctxs[b*64 + c] = proj_b[c] + dot4(proj_w + (size_t)c*128, h32 + b*128, 128);
    }
    // ==== theta init ====
#pragma unroll
    for (int e = 0; e < 4; ++e) {
        int idx = tid + e*256;
        int b = idx >> 8, i = idx & 255;
        th[idx] = wrapf(ctx_ang[((size_t)(b0 + b)*256 + 255)*256 + i]);
    }
    __syncthreads();

    // ==== SDE: 5 Euler steps ====
    for (int k = 0; k < 5; ++k) {
        for (int e = 0; e < 9; ++e) {            // inp = [sin th | cos th | ctx]
            int idx = tid + e*256;               // 0..2303
            int b = idx / 576;
            int i = idx - b*576;
            float vv;
            if (i < 256)       vv = __sinf(th[(b<<8) + i]);
            else if (i < 512)  vv = __cosf(th[(b<<8) + i - 256]);
            else               vv = ctxs[(b<<6) + i - 512];
            inp[idx] = vv;
        }
        __syncthreads();
#pragma unroll
        for (int e = 0; e < 2; ++e) {            // drift L0: 576 -> 128
            int o = tid*2 + e; int b = o >> 7, j = o & 127;
            hb1[o] = siluf(dr_b0[j] + dot4(dr_w0 + (size_t)j*576, inp + b*576, 576));
        }
        __syncthreads();
#pragma unroll
        for (int e = 0; e < 2; ++e) {            // drift L1
            int o = tid*2 + e; int b = o >> 7, j = o & 127;
            hb2[o] = siluf(dr_b1[j] + dot4(dr_w1 + (size_t)j*128, hb1 + b*128, 128));
        }
        __syncthreads();
#pragma unroll
        for (int e = 0; e < 2; ++e) {            // drift L2
            int o = tid*2 + e; int b = o >> 7, j = o & 127;
            hb1[o] = siluf(dr_b2[j] + dot4(dr_w2 + (size_t)j*128, hb2 + b*128, 128));
        }
        __syncthreads();
#pragma unroll
        for (int e = 0; e < 4; ++e) {            // drift L3: 128 -> 256 (mu)
            int o = tid + e*256; int b = o >> 8, j = o & 255;
            mus[o] = dr_b3[j] + dot4(dr_w3 + (size_t)j*128, hb1 + b*128, 128);
        }
        __syncthreads();
#pragma unroll
        for (int e = 0; e < 2; ++e) {            // diff L0: 576 -> 128
            int o = tid*2 + e; int b = o >> 7, j = o & 127;
            hb2[o] = siluf(df_b0[j] + dot4(df_w0 + (size_t)j*576, inp + b*576, 576));
        }
        __syncthreads();
#pragma unroll
        for (int e = 0; e < 2; ++e) {            // diff L1
            int o = tid*2 + e; int b = o >> 7, j = o & 127;
            hb1[o] = siluf(df_b1[j] + dot4(df_w1 + (size_t)j*128, hb2 + b*128, 128));
        }
        __syncthreads();
#pragma unroll
        for (int e = 0; e < 4; ++e) {            // diff L2 + softplus + theta update
            int o = tid + e*256; int b = o >> 8, j = o & 255;
            float a = df_b2[j] + dot4(df_w2 + (size_t)j*128, hb1 + b*128, 128);
            float sp = (a > 15.0f) ? a : log1pf(__expf(a));
            float sg = sp * DIFF_SCALE_F;
            float dw = dW[((size_t)(b0 + b)*5 + k)*256 + j];
            th[(b<<8) + j] = wrapf(th[(b<<8) + j] + mus[o]*DT_F + sg*dw);
        }
        __syncthreads();
    }

    // ==== write theta ====
#pragma unroll
    for (int e = 0; e < 4; ++e) {
        int idx = tid + e*256;
        out[(size_t)b0*256 + idx] = th[idx];
    }
}

extern "C" void kernel_launch(void* const* d_in, const int* in_sizes, int n_in,
                              void* d_out, int out_size, void* d_ws, size_t ws_size,
                              hipStream_t stream) {
    const float* ctx_ang = (const float*)d_in[0];
    const float* dW      = (const float*)d_in[1];
    const float* wih     = (const float*)d_in[2];
    const float* whh     = (const float*)d_in[3];
    const float* gru_b   = (const float*)d_in[4];
    const float* gru_bn  = (const float*)d_in[5];
    const float* proj_w  = (const float*)d_in[6];
    const float* proj_b  = (const float*)d_in[7];
    const float* dr_w0   = (const float*)d_in[8];
    const float* dr_b0   = (const float*)d_in[9];
    const float* dr_w1   = (const float*)d_in[10];
    const float* dr_b1   = (const float*)d_in[11];
    const float* dr_w2   = (const float*)d_in[12];
    const float* dr_b2   = (const float*)d_in[13];
    const float* dr_w3   = (const float*)d_in[14];
    const float* dr_b3   = (const float*)d_in[15];
    const float* df_w0   = (const float*)d_in[16];
    const float* df_b0   = (const float*)d_in[17];
    const float* df_w1   = (const float*)d_in[18];
    const float* df_b1   = (const float*)d_in[19];
    const float* df_w2   = (const float*)d_in[20];
    const float* df_b2   = (const float*)d_in[21];
    float* out = (float*)d_out;

    unsigned short* gi   = (unsigned short*)d_ws;              // 262144*384 bf16 = 201.3 MB
    unsigned short* wihb = gi + (size_t)262144*384;            // 384*512 bf16
    unsigned short* whhb = wihb + (size_t)384*512;             // 384*128 bf16

    prep_kernel<<<768, 256, 0, stream>>>(wih, whh, wihb, whhb);
    gi_gemm_kernel<<<2048, 512, 0, stream>>>(ctx_ang, wihb, gi);
    scan_sde_kernel<<<256, 256, 0, stream>>>(ctx_ang, dW, whhb, gru_b, gru_bn,
        proj_w, proj_b, dr_w0, dr_b0, dr_w1, dr_b1, dr_w2, dr_b2, dr_w3, dr_b3,
        df_w0, df_b0, df_w1, df_b1, df_w2, df_b2, gi, out);
}

// Round 3
// 1093.128 us; speedup vs baseline: 1.1147x; 1.1147x over previous
//
#include <hip/hip_runtime.h>
#include <stdint.h>

#define PI_F      3.14159265358979323846f
#define TWO_PI_F  6.28318530717958647692f
#define DT_F      0.05f
#define DIFF_SCALE_F 0.3f

typedef short short8 __attribute__((ext_vector_type(8)));
typedef float f32x4 __attribute__((ext_vector_type(4)));
typedef unsigned int u32x4 __attribute__((ext_vector_type(4)));

__device__ __forceinline__ unsigned short f2bf(float x) {
    unsigned int u = __float_as_uint(x);
    u += 0x7FFFu + ((u >> 16) & 1u);
    return (unsigned short)(u >> 16);
}
__device__ __forceinline__ float bf2f(unsigned short h) {
    return __uint_as_float(((unsigned int)h) << 16);
}
__device__ __forceinline__ float siluf(float x) {
    return x / (1.0f + __expf(-x));
}
__device__ __forceinline__ float wrapf(float t) {
    float w = fmodf(t + PI_F, TWO_PI_F);
    w = (w < 0.0f) ? w + TWO_PI_F : w;
    return w - PI_F;
}
__device__ __forceinline__ float dot4(const float* __restrict__ W, const float* __restrict__ X, int K) {
    float a = 0.0f;
#pragma unroll 4
    for (int kk = 0; kk < K; kk += 4) {
        f32x4 wv = *(const f32x4*)(W + kk);
        f32x4 xv = *(const f32x4*)(X + kk);
        a += wv[0]*xv[0] + wv[1]*xv[1] + wv[2]*xv[2] + wv[3]*xv[3];
    }
    return a;
}

// ---------------- K0: convert GRU weights to bf16 ----------------
__global__ void prep_kernel(const float* __restrict__ wih, const float* __restrict__ whh,
                            unsigned short* __restrict__ wihb, unsigned short* __restrict__ whhb) {
    int i = blockIdx.x * 256 + threadIdx.x;
    if (i < 384*512) wihb[i] = f2bf(wih[i]);
    if (i < 384*128) whhb[i] = f2bf(whh[i]);
}

// ---------------- K1: gi = [sin|cos](context) @ wih^T  (bf16 MFMA) ----------------
// Output: two planes, batch-granular:
//   P01[(t*1024+b)*128 + j] : u32 = (gate0 bf16 lo | gate1 bf16 hi)
//   P2 [(t*1024+b)*128 + j] : u16 = gate2 bf16
__launch_bounds__(512)
__global__ void gi_gemm_kernel(const float* __restrict__ ctx_ang,
                               const unsigned short* __restrict__ wihb,
                               unsigned int* __restrict__ P01,
                               unsigned short* __restrict__ P2) {
    __shared__ __align__(16) unsigned short As[2][128*64];  // [sin/cos][row][64 k], 16B-granule swizzled

    const int tid = threadIdx.x;
    const int lane = tid & 63;
    const int w  = tid >> 6;     // 0..7
    const int wm = w >> 2;       // 0..1 (M half)
    const int wn = w & 3;        // 0..3 (N quarter: 96 cols)
    const int l15 = lane & 15;
    const int l4  = lane >> 4;
    const int mt = blockIdx.x;   // 0..2047
    const int t  = mt >> 3;
    const int b0 = (mt & 7) * 128;

    const int srow = tid >> 2;   // 0..127 staging row
    const int q    = tid & 3;    // quarter of 64 d-values

    f32x4 acc[4][6];
    const f32x4 z4 = {0.0f, 0.0f, 0.0f, 0.0f};
#pragma unroll
    for (int mi = 0; mi < 4; ++mi)
#pragma unroll
        for (int ns = 0; ns < 6; ++ns) acc[mi][ns] = z4;

    for (int dt = 0; dt < 4; ++dt) {
        float v[16];
        {
            const float* src = ctx_ang + ((size_t)(b0 + srow) * 256 + t) * 256 + dt*64 + q*16;
#pragma unroll
            for (int j = 0; j < 4; ++j) {
                f32x4 x = *(const f32x4*)(src + j*4);
#pragma unroll
                for (int i = 0; i < 4; ++i) v[j*4+i] = x[i];
            }
        }
        unsigned int us[8], uc[8];
#pragma unroll
        for (int p = 0; p < 8; ++p) {
            float a0 = v[2*p], a1 = v[2*p+1];
            us[p] = (unsigned int)f2bf(__sinf(a0)) | ((unsigned int)f2bf(__sinf(a1)) << 16);
            uc[p] = (unsigned int)f2bf(__cosf(a0)) | ((unsigned int)f2bf(__cosf(a1)) << 16);
        }
        __syncthreads();
#pragma unroll
        for (int gg = 0; gg < 2; ++gg) {
            int g  = q*2 + gg;
            int gs = g ^ (srow & 7);
            u32x4 ws = { us[gg*4+0], us[gg*4+1], us[gg*4+2], us[gg*4+3] };
            u32x4 wc = { uc[gg*4+0], uc[gg*4+1], uc[gg*4+2], uc[gg*4+3] };
            *(u32x4*)((char*)&As[0][0] + srow*128 + gs*16) = ws;
            *(u32x4*)((char*)&As[1][0] + srow*128 + gs*16) = wc;
        }
        __syncthreads();

#pragma unroll
        for (int half = 0; half < 2; ++half) {
            const char* Ab = (const char*)&As[half][0];
            const int kbase = half*256 + dt*64;
#pragma unroll
            for (int ki = 0; ki < 2; ++ki) {
                short8 aF[4], bF[6];
#pragma unroll
                for (int mi = 0; mi < 4; ++mi) {
                    int row = wm*64 + mi*16 + l15;
                    int kg  = ki*4 + l4;
                    aF[mi] = *(const short8*)(Ab + row*128 + ((kg ^ (row & 7)))*16);
                }
#pragma unroll
                for (int ns = 0; ns < 6; ++ns) {
                    int col = wn*96 + ns*16 + l15;
                    bF[ns] = *(const short8*)(wihb + (size_t)col*512 + kbase + ki*32 + l4*8);
                }
#pragma unroll
                for (int mi = 0; mi < 4; ++mi)
#pragma unroll
                    for (int ns = 0; ns < 6; ++ns)
                        acc[mi][ns] = __builtin_amdgcn_mfma_f32_16x16x32_bf16(aF[mi], bF[ns], acc[mi][ns], 0, 0, 0);
            }
        }
    }

    // --- epilogue: scatter bf16 into P01/P2 planes ---
#pragma unroll
    for (int mi = 0; mi < 4; ++mi) {
#pragma unroll
        for (int ns = 0; ns < 6; ++ns) {
            int col = wn*96 + ns*16 + l15;
            int g = col >> 7, j = col & 127;     // g wave-uniform (tiles never straddle 128)
#pragma unroll
            for (int r = 0; r < 4; ++r) {
                int b = b0 + wm*64 + mi*16 + l4*4 + r;
                size_t idx = ((size_t)t*1024 + b)*128 + j;
                unsigned short vv = f2bf(acc[mi][ns][r]);
                if (g < 2) ((unsigned short*)P01)[idx*2 + g] = vv;
                else       P2[idx] = vv;
            }
        }
    }
}

// ---------------- K2: GRU scan (8 waves, 2 batches/block) ----------------

#define SYNC_RAW() do { \
    asm volatile("s_waitcnt lgkmcnt(0)" ::: "memory"); \
    __builtin_amdgcn_s_barrier(); \
    __builtin_amdgcn_sched_barrier(0); \
} while (0)

#define LOADPF(PF, tt) do { \
    if ((tt) < 256 && l4 == 0) { \
        size_t _i = ((size_t)(tt)*1024 + b0)*128 + j; \
        PF[0] = P01[_i]; PF[1] = P01[_i + 128]; \
        PF[2] = P2[_i];  PF[3] = P2[_i + 128]; \
    } \
} while (0)

#define STEP(RDBUF, WRBUF, PF) do { \
    short8 aF[4]; \
    _Pragma("unroll") \
    for (int kt = 0; kt < 4; ++kt) \
        aF[kt] = *(const short8*)((const char*)(RDBUF) + l15*256 + (((kt*4 + l4) ^ (l15 & 7)))*16); \
    f32x4 a0 = z4, a1 = z4, a2 = z4; \
    _Pragma("unroll") \
    for (int kt = 0; kt < 4; ++kt) { \
        a0 = __builtin_amdgcn_mfma_f32_16x16x32_bf16(aF[kt], whB0[kt], a0, 0, 0, 0); \
        a1 = __builtin_amdgcn_mfma_f32_16x16x32_bf16(aF[kt], whB1[kt], a1, 0, 0, 0); \
        a2 = __builtin_amdgcn_mfma_f32_16x16x32_bf16(aF[kt], whB2[kt], a2, 0, 0, 0); \
    } \
    _Pragma("unroll") \
    for (int rb = 0; rb < 2; ++rb) { \
        float ir  = bf2f((unsigned short)(PF[rb] & 0xFFFFu)) + bR; \
        float iz  = bf2f((unsigned short)(PF[rb] >> 16))     + bZ; \
        float in_ = bf2f((unsigned short)(PF[2 + rb]))       + bN; \
        float rg = __builtin_amdgcn_rcpf(1.0f + __expf(-(ir + a0[rb]))); \
        float zg = __builtin_amdgcn_rcpf(1.0f + __expf(-(iz + a1[rb]))); \
        float ng = 1.0f - 2.0f*__builtin_amdgcn_rcpf(1.0f + __expf(2.0f*(in_ + rg*(a2[rb] + bBN)))); \
        float hnew = ng + zg*(H[rb] - ng); \
        H[rb] = hnew; \
        if (l4 == 0) \
            *(unsigned short*)((char*)(WRBUF) + rb*256 + ((jg ^ rb))*16 + (j & 7)*2) = f2bf(hnew); \
    } \
} while (0)

__launch_bounds__(512, 4)
__global__ void scan_kernel(const unsigned int* __restrict__ P01,
                            const unsigned short* __restrict__ P2,
                            const unsigned short* __restrict__ whhb,
                            const float* __restrict__ gru_b,
                            const float* __restrict__ gru_bn,
                            float* __restrict__ h_ws) {
    __shared__ __align__(16) unsigned short hAbuf[2][16*128];  // rows 0,1 live; rows 2-15 zero

    const int tid  = threadIdx.x;
    const int lane = tid & 63;
    const int w    = tid >> 6;        // wave 0..7, owns cols w*16..w*16+15 per gate
    const int l15  = lane & 15;
    const int l4   = lane >> 4;
    const int b0   = blockIdx.x * 2;  // batches b0, b0+1
    const int j    = w*16 + l15;      // hidden col
    const int jg   = j >> 3;          // granule index

    // zero both buffers (512 threads x 16B = 8 KB)
    {
        u32x4 z = {0u,0u,0u,0u};
        *(u32x4*)((char*)hAbuf + tid*16) = z;
    }

    // whh B-fragments: 3 gates x 4 k-slices (48 VGPR)
    short8 whB0[4], whB1[4], whB2[4];
#pragma unroll
    for (int kt = 0; kt < 4; ++kt) {
        whB0[kt] = *(const short8*)(whhb + (size_t)(0*128 + j)*128 + kt*32 + l4*8);
        whB1[kt] = *(const short8*)(whhb + (size_t)(1*128 + j)*128 + kt*32 + l4*8);
        whB2[kt] = *(const short8*)(whhb + (size_t)(2*128 + j)*128 + kt*32 + l4*8);
    }
    const float bR  = gru_b[j];
    const float bZ  = gru_b[128 + j];
    const float bN  = gru_b[256 + j];
    const float bBN = gru_bn[j];

    float H[2] = {0.f, 0.f};
    const f32x4 z4 = {0.0f,0.0f,0.0f,0.0f};

    unsigned int PFa[4] = {0,0,0,0}, PFb[4] = {0,0,0,0}, PFc[4] = {0,0,0,0}, PFd[4] = {0,0,0,0};
    LOADPF(PFa, 0);
    LOADPF(PFb, 1);
    LOADPF(PFc, 2);
    LOADPF(PFd, 3);
    __syncthreads();

    for (int t = 0; t < 256; t += 4) {
        STEP(&hAbuf[0][0], &hAbuf[1][0], PFa); LOADPF(PFa, t + 4); SYNC_RAW();
        STEP(&hAbuf[1][0], &hAbuf[0][0], PFb); LOADPF(PFb, t + 5); SYNC_RAW();
        STEP(&hAbuf[0][0], &hAbuf[1][0], PFc); LOADPF(PFc, t + 6); SYNC_RAW();
        STEP(&hAbuf[1][0], &hAbuf[0][0], PFd); LOADPF(PFd, t + 7); SYNC_RAW();
    }

    if (l4 == 0) {
        h_ws[(size_t)(b0 + 0)*128 + j] = H[0];
        h_ws[(size_t)(b0 + 1)*128 + j] = H[1];
    }
}

// ---------------- K3: proj + SDE (4 batches/block) ----------------
__launch_bounds__(256)
__global__ void sde_kernel(const float* __restrict__ ctx_ang,
                           const float* __restrict__ dW,
                           const float* __restrict__ proj_w,
                           const float* __restrict__ proj_b,
                           const float* __restrict__ dr_w0, const float* __restrict__ dr_b0,
                           const float* __restrict__ dr_w1, const float* __restrict__ dr_b1,
                           const float* __restrict__ dr_w2, const float* __restrict__ dr_b2,
                           const float* __restrict__ dr_w3, const float* __restrict__ dr_b3,
                           const float* __restrict__ df_w0, const float* __restrict__ df_b0,
                           const float* __restrict__ df_w1, const float* __restrict__ df_b1,
                           const float* __restrict__ df_w2, const float* __restrict__ df_b2,
                           const float* __restrict__ h_ws,
                           float* __restrict__ out) {
    __shared__ __align__(16) float h32[4*128];
    __shared__ __align__(16) float th[4*256];
    __shared__ __align__(16) float ctxs[4*64];
    __shared__ __align__(16) float inp[4*576];
    __shared__ __align__(16) float hb1[4*128];
    __shared__ __align__(16) float hb2[4*128];
    __shared__ __align__(16) float mus[4*256];

    const int tid = threadIdx.x;
    const int b0  = blockIdx.x * 4;

#pragma unroll
    for (int e = 0; e < 2; ++e)
        h32[tid + e*256] = h_ws[(size_t)b0*128 + tid + e*256];
    __syncthreads();

    {
        int b = tid >> 6, c = tid & 63;
        ctxs[b*64 + c] = proj_b[c] + dot4(proj_w + (size_t)c*128, h32 + b*128, 128);
    }
#pragma unroll
    for (int e = 0; e < 4; ++e) {
        int idx = tid + e*256;
        int b = idx >> 8, i = idx & 255;
        th[idx] = wrapf(ctx_ang[((size_t)(b0 + b)*256 + 255)*256 + i]);
    }
    __syncthreads();

    for (int k = 0; k < 5; ++k) {
        for (int e = 0; e < 9; ++e) {
            int idx = tid + e*256;
            int b = idx / 576;
            int i = idx - b*576;
            float vv;
            if (i < 256)       vv = __sinf(th[(b<<8) + i]);
            else if (i < 512)  vv = __cosf(th[(b<<8) + i - 256]);
            else               vv = ctxs[(b<<6) + i - 512];
            inp[idx] = vv;
        }
        __syncthreads();
#pragma unroll
        for (int e = 0; e < 2; ++e) {
            int o = tid*2 + e; int b = o >> 7, jj = o & 127;
            hb1[o] = siluf(dr_b0[jj] + dot4(dr_w0 + (size_t)jj*576, inp + b*576, 576));
        }
        __syncthreads();
#pragma unroll
        for (int e = 0; e < 2; ++e) {
            int o = tid*2 + e; int b = o >> 7, jj = o & 127;
            hb2[o] = siluf(dr_b1[jj] + dot4(dr_w1 + (size_t)jj*128, hb1 + b*128, 128));
        }
        __syncthreads();
#pragma unroll
        for (int e = 0; e < 2; ++e) {
            int o = tid*2 + e; int b = o >> 7, jj = o & 127;
            hb1[o] = siluf(dr_b2[jj] + dot4(dr_w2 + (size_t)jj*128, hb2 + b*128, 128));
        }
        __syncthreads();
#pragma unroll
        for (int e = 0; e < 4; ++e) {
            int o = tid + e*256; int b = o >> 8, jj = o & 255;
            mus[o] = dr_b3[jj] + dot4(dr_w3 + (size_t)jj*128, hb1 + b*128, 128);
        }
        __syncthreads();
#pragma unroll
        for (int e = 0; e < 2; ++e) {
            int o = tid*2 + e; int b = o >> 7, jj = o & 127;
            hb2[o] = siluf(df_b0[jj] + dot4(df_w0 + (size_t)jj*576, inp + b*576, 576));
        }
        __syncthreads();
#pragma unroll
        for (int e = 0; e < 2; ++e) {
            int o = tid*2 + e; int b = o >> 7, jj = o & 127;
            hb1[o] = siluf(df_b1[jj] + dot4(df_w1 + (size_t)jj*128, hb2 + b*128, 128));
        }
        __syncthreads();
#pragma unroll
        for (int e = 0; e < 4; ++e) {
            int o = tid + e*256; int b = o >> 8, jj = o & 255;
            float a = df_b2[jj] + dot4(df_w2 + (size_t)jj*128, hb1 + b*128, 128);
            float sp = (a > 15.0f) ? a : log1pf(__expf(a));
            float sg = sp * DIFF_SCALE_F;
            float dw = dW[((size_t)(b0 + b)*5 + k)*256 + jj];
            th[(b<<8) + jj] = wrapf(th[(b<<8) + jj] + mus[o]*DT_F + sg*dw);
        }
        __syncthreads();
    }

#pragma unroll
    for (int e = 0; e < 4; ++e) {
        int idx = tid + e*256;
        out[(size_t)b0*256 + idx] = th[idx];
    }
}

extern "C" void kernel_launch(void* const* d_in, const int* in_sizes, int n_in,
                              void* d_out, int out_size, void* d_ws, size_t ws_size,
                              hipStream_t stream) {
    const float* ctx_ang = (const float*)d_in[0];
    const float* dW      = (const float*)d_in[1];
    const float* wih     = (const float*)d_in[2];
    const float* whh     = (const float*)d_in[3];
    const float* gru_b   = (const float*)d_in[4];
    const float* gru_bn  = (const float*)d_in[5];
    const float* proj_w  = (const float*)d_in[6];
    const float* proj_b  = (const float*)d_in[7];
    const float* dr_w0   = (const float*)d_in[8];
    const float* dr_b0   = (const float*)d_in[9];
    const float* dr_w1   = (const float*)d_in[10];
    const float* dr_b1   = (const float*)d_in[11];
    const float* dr_w2   = (const float*)d_in[12];
    const float* dr_b2   = (const float*)d_in[13];
    const float* dr_w3   = (const float*)d_in[14];
    const float* dr_b3   = (const float*)d_in[15];
    const float* df_w0   = (const float*)d_in[16];
    const float* df_b0   = (const float*)d_in[17];
    const float* df_w1   = (const float*)d_in[18];
    const float* df_b1   = (const float*)d_in[19];
    const float* df_w2   = (const float*)d_in[20];
    const float* df_b2   = (const float*)d_in[21];
    float* out = (float*)d_out;

    char* ws = (char*)d_ws;
    unsigned int*   P01  = (unsigned int*)ws;                         // 134,217,728 B
    unsigned short* P2   = (unsigned short*)(ws + 134217728);         //  67,108,864 B
    unsigned short* wihb = (unsigned short*)(ws + 201326592);         //     393,216 B
    unsigned short* whhb = (unsigned short*)(ws + 201719808);         //      98,304 B
    float*          h_ws = (float*)(ws + 201818112);                  //     524,288 B

    prep_kernel<<<768, 256, 0, stream>>>(wih, whh, wihb, whhb);
    gi_gemm_kernel<<<2048, 512, 0, stream>>>(ctx_ang, wihb, P01, P2);
    scan_kernel<<<512, 512, 0, stream>>>(P01, P2, whhb, gru_b, gru_bn, h_ws);
    sde_kernel<<<256, 256, 0, stream>>>(ctx_ang, dW,
        proj_w, proj_b, dr_w0, dr_b0, dr_w1, dr_b1, dr_w2, dr_b2, dr_w3, dr_b3,
        df_w0, df_b0, df_w1, df_b1, df_w2, df_b2, h_ws, out);
}

// Round 4
// 671.614 us; speedup vs baseline: 1.8143x; 1.6276x over previous
//
#include <hip/hip_runtime.h>
#include <stdint.h>

#define PI_F      3.14159265358979323846f
#define TWO_PI_F  6.28318530717958647692f
#define DT_F      0.05f
#define DIFF_SCALE_F 0.3f

typedef short short8 __attribute__((ext_vector_type(8)));
typedef float f32x4 __attribute__((ext_vector_type(4)));
typedef unsigned int u32x4 __attribute__((ext_vector_type(4)));

__device__ __forceinline__ unsigned short f2bf(float x) {
    unsigned int u = __float_as_uint(x);
    u += 0x7FFFu + ((u >> 16) & 1u);
    return (unsigned short)(u >> 16);
}
__device__ __forceinline__ float bf2f(unsigned short h) {
    return __uint_as_float(((unsigned int)h) << 16);
}
__device__ __forceinline__ float siluf(float x) {
    return x / (1.0f + __expf(-x));
}
__device__ __forceinline__ float wrapf(float t) {
    float w = fmodf(t + PI_F, TWO_PI_F);
    w = (w < 0.0f) ? w + TWO_PI_F : w;
    return w - PI_F;
}
__device__ __forceinline__ float dot4(const float* __restrict__ W, const float* __restrict__ X, int K) {
    float a = 0.0f;
#pragma unroll 4
    for (int kk = 0; kk < K; kk += 4) {
        f32x4 wv = *(const f32x4*)(W + kk);
        f32x4 xv = *(const f32x4*)(X + kk);
        a += wv[0]*xv[0] + wv[1]*xv[1] + wv[2]*xv[2] + wv[3]*xv[3];
    }
    return a;
}

// ---------------- K0: convert GRU weights to bf16 ----------------
__global__ void prep_kernel(const float* __restrict__ wih, const float* __restrict__ whh,
                            unsigned short* __restrict__ wihb, unsigned short* __restrict__ whhb) {
    int i = blockIdx.x * 256 + threadIdx.x;
    if (i < 384*512) wihb[i] = f2bf(wih[i]);
    if (i < 384*128) whhb[i] = f2bf(whh[i]);
}

// ---------------- K0b: convert SDE MLP weights to bf16 (into dead P01 region) ----------------
__global__ void prep2_kernel(const float* __restrict__ dr_w0, const float* __restrict__ dr_w1,
                             const float* __restrict__ dr_w2, const float* __restrict__ dr_w3,
                             const float* __restrict__ df_w0, const float* __restrict__ df_w1,
                             const float* __restrict__ df_w2,
                             unsigned short* __restrict__ dst) {
    int i = blockIdx.x * 256 + threadIdx.x;   // 0..262143
    const float* src; int off;
    if      (i < 73728)  { src = dr_w0; off = 0; }
    else if (i < 90112)  { src = dr_w1; off = 73728; }
    else if (i < 106496) { src = dr_w2; off = 90112; }
    else if (i < 139264) { src = dr_w3; off = 106496; }
    else if (i < 212992) { src = df_w0; off = 139264; }
    else if (i < 229376) { src = df_w1; off = 212992; }
    else                 { src = df_w2; off = 229376; }
    dst[i] = f2bf(src[i - off]);
}

// ---------------- K1: gi = [sin|cos](context) @ wih^T  (bf16 MFMA) ----------------
__launch_bounds__(512)
__global__ void gi_gemm_kernel(const float* __restrict__ ctx_ang,
                               const unsigned short* __restrict__ wihb,
                               unsigned int* __restrict__ P01,
                               unsigned short* __restrict__ P2) {
    __shared__ __align__(16) unsigned short As[2][128*64];

    const int tid = threadIdx.x;
    const int lane = tid & 63;
    const int w  = tid >> 6;
    const int wm = w >> 2;
    const int wn = w & 3;
    const int l15 = lane & 15;
    const int l4  = lane >> 4;
    const int mt = blockIdx.x;
    const int t  = mt >> 3;
    const int b0 = (mt & 7) * 128;

    const int srow = tid >> 2;
    const int q    = tid & 3;

    f32x4 acc[4][6];
    const f32x4 z4 = {0.0f, 0.0f, 0.0f, 0.0f};
#pragma unroll
    for (int mi = 0; mi < 4; ++mi)
#pragma unroll
        for (int ns = 0; ns < 6; ++ns) acc[mi][ns] = z4;

    for (int dt = 0; dt < 4; ++dt) {
        float v[16];
        {
            const float* src = ctx_ang + ((size_t)(b0 + srow) * 256 + t) * 256 + dt*64 + q*16;
#pragma unroll
            for (int j = 0; j < 4; ++j) {
                f32x4 x = *(const f32x4*)(src + j*4);
#pragma unroll
                for (int i = 0; i < 4; ++i) v[j*4+i] = x[i];
            }
        }
        unsigned int us[8], uc[8];
#pragma unroll
        for (int p = 0; p < 8; ++p) {
            float a0 = v[2*p], a1 = v[2*p+1];
            us[p] = (unsigned int)f2bf(__sinf(a0)) | ((unsigned int)f2bf(__sinf(a1)) << 16);
            uc[p] = (unsigned int)f2bf(__cosf(a0)) | ((unsigned int)f2bf(__cosf(a1)) << 16);
        }
        __syncthreads();
#pragma unroll
        for (int gg = 0; gg < 2; ++gg) {
            int g  = q*2 + gg;
            int gs = g ^ (srow & 7);
            u32x4 ws = { us[gg*4+0], us[gg*4+1], us[gg*4+2], us[gg*4+3] };
            u32x4 wc = { uc[gg*4+0], uc[gg*4+1], uc[gg*4+2], uc[gg*4+3] };
            *(u32x4*)((char*)&As[0][0] + srow*128 + gs*16) = ws;
            *(u32x4*)((char*)&As[1][0] + srow*128 + gs*16) = wc;
        }
        __syncthreads();

#pragma unroll
        for (int half = 0; half < 2; ++half) {
            const char* Ab = (const char*)&As[half][0];
            const int kbase = half*256 + dt*64;
#pragma unroll
            for (int ki = 0; ki < 2; ++ki) {
                short8 aF[4], bF[6];
#pragma unroll
                for (int mi = 0; mi < 4; ++mi) {
                    int row = wm*64 + mi*16 + l15;
                    int kg  = ki*4 + l4;
                    aF[mi] = *(const short8*)(Ab + row*128 + ((kg ^ (row & 7)))*16);
                }
#pragma unroll
                for (int ns = 0; ns < 6; ++ns) {
                    int col = wn*96 + ns*16 + l15;
                    bF[ns] = *(const short8*)(wihb + (size_t)col*512 + kbase + ki*32 + l4*8);
                }
#pragma unroll
                for (int mi = 0; mi < 4; ++mi)
#pragma unroll
                    for (int ns = 0; ns < 6; ++ns)
                        acc[mi][ns] = __builtin_amdgcn_mfma_f32_16x16x32_bf16(aF[mi], bF[ns], acc[mi][ns], 0, 0, 0);
            }
        }
    }

#pragma unroll
    for (int mi = 0; mi < 4; ++mi) {
#pragma unroll
        for (int ns = 0; ns < 6; ++ns) {
            int col = wn*96 + ns*16 + l15;
            int g = col >> 7, j = col & 127;
#pragma unroll
            for (int r = 0; r < 4; ++r) {
                int b = b0 + wm*64 + mi*16 + l4*4 + r;
                size_t idx = ((size_t)t*1024 + b)*128 + j;
                unsigned short vv = f2bf(acc[mi][ns][r]);
                if (g < 2) ((unsigned short*)P01)[idx*2 + g] = vv;
                else       P2[idx] = vv;
            }
        }
    }
}

// ---------------- K2: GRU scan (8 waves, 2 batches/block) ----------------

#define SYNC_RAW() do { \
    asm volatile("s_waitcnt lgkmcnt(0)" ::: "memory"); \
    __builtin_amdgcn_s_barrier(); \
    __builtin_amdgcn_sched_barrier(0); \
} while (0)

#define LOADPF(PF, tt) do { \
    if ((tt) < 256 && l4 == 0) { \
        size_t _i = ((size_t)(tt)*1024 + b0)*128 + j; \
        PF[0] = P01[_i]; PF[1] = P01[_i + 128]; \
        PF[2] = P2[_i];  PF[3] = P2[_i + 128]; \
    } \
} while (0)

#define STEP(RDBUF, WRBUF, PF) do { \
    short8 aF[4]; \
    _Pragma("unroll") \
    for (int kt = 0; kt < 4; ++kt) \
        aF[kt] = *(const short8*)((const char*)(RDBUF) + l15*256 + (((kt*4 + l4) ^ (l15 & 7)))*16); \
    f32x4 a0 = z4, a1 = z4, a2 = z4; \
    _Pragma("unroll") \
    for (int kt = 0; kt < 4; ++kt) { \
        a0 = __builtin_amdgcn_mfma_f32_16x16x32_bf16(aF[kt], whB0[kt], a0, 0, 0, 0); \
        a1 = __builtin_amdgcn_mfma_f32_16x16x32_bf16(aF[kt], whB1[kt], a1, 0, 0, 0); \
        a2 = __builtin_amdgcn_mfma_f32_16x16x32_bf16(aF[kt], whB2[kt], a2, 0, 0, 0); \
    } \
    _Pragma("unroll") \
    for (int rb = 0; rb < 2; ++rb) { \
        float ir  = bf2f((unsigned short)(PF[rb] & 0xFFFFu)) + bR; \
        float iz  = bf2f((unsigned short)(PF[rb] >> 16))     + bZ; \
        float in_ = bf2f((unsigned short)(PF[2 + rb]))       + bN; \
        float rg = __builtin_amdgcn_rcpf(1.0f + __expf(-(ir + a0[rb]))); \
        float zg = __builtin_amdgcn_rcpf(1.0f + __expf(-(iz + a1[rb]))); \
        float ng = 1.0f - 2.0f*__builtin_amdgcn_rcpf(1.0f + __expf(2.0f*(in_ + rg*(a2[rb] + bBN)))); \
        float hnew = ng + zg*(H[rb] - ng); \
        H[rb] = hnew; \
        if (l4 == 0) \
            *(unsigned short*)((char*)(WRBUF) + rb*256 + ((jg ^ rb))*16 + (j & 7)*2) = f2bf(hnew); \
    } \
} while (0)

__launch_bounds__(512, 4)
__global__ void scan_kernel(const unsigned int* __restrict__ P01,
                            const unsigned short* __restrict__ P2,
                            const unsigned short* __restrict__ whhb,
                            const float* __restrict__ gru_b,
                            const float* __restrict__ gru_bn,
                            float* __restrict__ h_ws) {
    __shared__ __align__(16) unsigned short hAbuf[2][16*128];

    const int tid  = threadIdx.x;
    const int lane = tid & 63;
    const int w    = tid >> 6;
    const int l15  = lane & 15;
    const int l4   = lane >> 4;
    const int b0   = blockIdx.x * 2;
    const int j    = w*16 + l15;
    const int jg   = j >> 3;

    {
        u32x4 z = {0u,0u,0u,0u};
        *(u32x4*)((char*)hAbuf + tid*16) = z;
    }

    short8 whB0[4], whB1[4], whB2[4];
#pragma unroll
    for (int kt = 0; kt < 4; ++kt) {
        whB0[kt] = *(const short8*)(whhb + (size_t)(0*128 + j)*128 + kt*32 + l4*8);
        whB1[kt] = *(const short8*)(whhb + (size_t)(1*128 + j)*128 + kt*32 + l4*8);
        whB2[kt] = *(const short8*)(whhb + (size_t)(2*128 + j)*128 + kt*32 + l4*8);
    }
    const float bR  = gru_b[j];
    const float bZ  = gru_b[128 + j];
    const float bN  = gru_b[256 + j];
    const float bBN = gru_bn[j];

    float H[2] = {0.f, 0.f};
    const f32x4 z4 = {0.0f,0.0f,0.0f,0.0f};

    unsigned int PFa[4] = {0,0,0,0}, PFb[4] = {0,0,0,0}, PFc[4] = {0,0,0,0}, PFd[4] = {0,0,0,0};
    LOADPF(PFa, 0);
    LOADPF(PFb, 1);
    LOADPF(PFc, 2);
    LOADPF(PFd, 3);
    __syncthreads();

    for (int t = 0; t < 256; t += 4) {
        STEP(&hAbuf[0][0], &hAbuf[1][0], PFa); LOADPF(PFa, t + 4); SYNC_RAW();
        STEP(&hAbuf[1][0], &hAbuf[0][0], PFb); LOADPF(PFb, t + 5); SYNC_RAW();
        STEP(&hAbuf[0][0], &hAbuf[1][0], PFc); LOADPF(PFc, t + 6); SYNC_RAW();
        STEP(&hAbuf[1][0], &hAbuf[0][0], PFd); LOADPF(PFd, t + 7); SYNC_RAW();
    }

    if (l4 == 0) {
        h_ws[(size_t)(b0 + 0)*128 + j] = H[0];
        h_ws[(size_t)(b0 + 1)*128 + j] = H[1];
    }
}

// ---------------- K3: proj + SDE, MFMA, 16 batches/block ----------------
// A-fragment read from swizzled row-major [16][C] bf16 LDS (row stride S bytes)
#define AFRAG(BUF, S, ks) (*(const short8*)((const char*)(BUF) + l15*(S) + ((((ks)*4 + l4) ^ (l15 & 7))*16)))
// B-fragment from row-major bf16 weights [N][K]
#define BFRAG(W, jj, K, ks) (*(const short8*)((W) + (size_t)(jj)*(K) + (ks)*32 + l4*8))
// store bf16 into swizzled [16][128] hidden buffer
#define HSTORE(BUF, bb, col, val) (*(unsigned short*)((char*)(BUF) + (bb)*256 + ((((col)>>3) ^ ((bb)&7))*16) + ((col)&7)*2) = f2bf(val))
#define MFMA16(af, bf, c) __builtin_amdgcn_mfma_f32_16x16x32_bf16((af), (bf), (c), 0, 0, 0)

__launch_bounds__(512, 1)
__global__ void sde_kernel(const float* __restrict__ ctx_ang,
                           const float* __restrict__ dW,
                           const float* __restrict__ proj_w,
                           const float* __restrict__ proj_b,
                           const float* __restrict__ dr_b0, const float* __restrict__ dr_b1,
                           const float* __restrict__ dr_b2, const float* __restrict__ dr_b3,
                           const float* __restrict__ df_b0, const float* __restrict__ df_b1,
                           const float* __restrict__ df_b2,
                           const unsigned short* __restrict__ W0d, const unsigned short* __restrict__ W1d,
                           const unsigned short* __restrict__ W2d, const unsigned short* __restrict__ W3d,
                           const unsigned short* __restrict__ W0f, const unsigned short* __restrict__ W1f,
                           const unsigned short* __restrict__ W2f,
                           const float* __restrict__ h_ws,
                           float* __restrict__ out) {
    __shared__ __align__(16) float th[16*256];            // 16 KB
    __shared__ __align__(16) float ctxs[16*64];           // 4 KB
    __shared__ __align__(16) float h32[16*128];           // 8 KB
    __shared__ __align__(16) unsigned short inpA[16*576]; // 18 KB, swizzled
    __shared__ __align__(16) unsigned short hA[16*128], hB[16*128], hC[16*128], hD[16*128]; // 16 KB
    __shared__ __align__(16) float sgs[16*256];           // 16 KB

    const int tid  = threadIdx.x;
    const int lane = tid & 63;
    const int w    = tid >> 6;      // 0..7
    const int l15  = lane & 15;
    const int l4   = lane >> 4;
    const int b0   = blockIdx.x * 16;
    const f32x4 z4 = {0.f,0.f,0.f,0.f};

    // load final h, proj to ctx, init theta
#pragma unroll
    for (int e = 0; e < 4; ++e)
        h32[tid + e*512] = h_ws[(size_t)b0*128 + tid + e*512];
    __syncthreads();
#pragma unroll
    for (int e = 0; e < 2; ++e) {
        int o = tid*2 + e; int b = o >> 6, c = o & 63;
        ctxs[o] = proj_b[c] + dot4(proj_w + (size_t)c*128, h32 + b*128, 128);
    }
#pragma unroll
    for (int e = 0; e < 8; ++e) {
        int idx = tid + e*512; int b = idx >> 8, i = idx & 255;
        th[idx] = wrapf(ctx_ang[((size_t)(b0 + b)*256 + 255)*256 + i]);
    }

    // hoisted per-lane biases
    const int j  = w*16 + l15;        // 128-wide col
    const int j20 = w*32 + l15;       // 256-wide cols (2 tiles)
    const int j21 = w*32 + 16 + l15;
    const float bd0 = dr_b0[j], bd1 = dr_b1[j], bd2 = dr_b2[j];
    const float bf0 = df_b0[j], bf1 = df_b1[j];
    const float bd3t0 = dr_b3[j20], bd3t1 = dr_b3[j21];
    const float bf2t0 = df_b2[j20], bf2t1 = df_b2[j21];
    __syncthreads();

    for (int k = 0; k < 5; ++k) {
        // build inpA = [sin th | cos th | ctx] bf16, swizzled
        {
            int b = tid >> 5, i0 = (tid & 31) * 18;
#pragma unroll
            for (int ii = 0; ii < 18; ++ii) {
                int i = i0 + ii;
                float vv;
                if (i < 256)      vv = __sinf(th[b*256 + i]);
                else if (i < 512) vv = __cosf(th[b*256 + i - 256]);
                else              vv = ctxs[b*64 + i - 512];
                *(unsigned short*)((char*)inpA + b*1152 + (((i>>3) ^ (b&7))*16) + (i&7)*2) = f2bf(vv);
            }
        }
        __syncthreads();

        // p1: drift L0 (inpA->hA) || diff L0 (inpA->hC), K=576
        {
            f32x4 a0=z4,a1=z4,c0=z4,c1=z4;
#pragma unroll
            for (int ks = 0; ks < 18; ks += 2) {
                short8 af0 = AFRAG(inpA, 1152, ks);
                short8 af1 = AFRAG(inpA, 1152, ks+1);
                a0 = MFMA16(af0, BFRAG(W0d, j, 576, ks),   a0);
                c0 = MFMA16(af0, BFRAG(W0f, j, 576, ks),   c0);
                a1 = MFMA16(af1, BFRAG(W0d, j, 576, ks+1), a1);
                c1 = MFMA16(af1, BFRAG(W0f, j, 576, ks+1), c1);
            }
#pragma unroll
            for (int r = 0; r < 4; ++r) {
                int bb = l4*4 + r;
                HSTORE(hA, bb, j, siluf(a0[r] + a1[r] + bd0));
                HSTORE(hC, bb, j, siluf(c0[r] + c1[r] + bf0));
            }
        }
        __syncthreads();

        // p2: drift L1 (hA->hB) || diff L1 (hC->hD), K=128
        {
            f32x4 a0=z4,a1=z4,c0=z4,c1=z4;
#pragma unroll
            for (int ks = 0; ks < 4; ks += 2) {
                short8 aA0 = AFRAG(hA, 256, ks), aA1 = AFRAG(hA, 256, ks+1);
                short8 aC0 = AFRAG(hC, 256, ks), aC1 = AFRAG(hC, 256, ks+1);
                a0 = MFMA16(aA0, BFRAG(W1d, j, 128, ks),   a0);
                c0 = MFMA16(aC0, BFRAG(W1f, j, 128, ks),   c0);
                a1 = MFMA16(aA1, BFRAG(W1d, j, 128, ks+1), a1);
                c1 = MFMA16(aC1, BFRAG(W1f, j, 128, ks+1), c1);
            }
#pragma unroll
            for (int r = 0; r < 4; ++r) {
                int bb = l4*4 + r;
                HSTORE(hB, bb, j, siluf(a0[r] + a1[r] + bd1));
                HSTORE(hD, bb, j, siluf(c0[r] + c1[r] + bf1));
            }
        }
        __syncthreads();

        // p3: drift L2 (hB->hA) || diff L2 (hD->sgs, N=256), K=128
        {
            f32x4 a0=z4,a1=z4,s0=z4,s1=z4,s2=z4,s3=z4;
#pragma unroll
            for (int ks = 0; ks < 4; ks += 2) {
                short8 b0f = AFRAG(hB, 256, ks), b1f = AFRAG(hB, 256, ks+1);
                short8 d0f = AFRAG(hD, 256, ks), d1f = AFRAG(hD, 256, ks+1);
                a0 = MFMA16(b0f, BFRAG(W2d, j,   128, ks),   a0);
                a1 = MFMA16(b1f, BFRAG(W2d, j,   128, ks+1), a1);
                s0 = MFMA16(d0f, BFRAG(W2f, j20, 128, ks),   s0);
                s1 = MFMA16(d1f, BFRAG(W2f, j20, 128, ks+1), s1);
                s2 = MFMA16(d0f, BFRAG(W2f, j21, 128, ks),   s2);
                s3 = MFMA16(d1f, BFRAG(W2f, j21, 128, ks+1), s3);
            }
#pragma unroll
            for (int r = 0; r < 4; ++r) {
                int bb = l4*4 + r;
                HSTORE(hA, bb, j, siluf(a0[r] + a1[r] + bd2));
                float aa0 = s0[r] + s1[r] + bf2t0;
                float aa1 = s2[r] + s3[r] + bf2t1;
                float sp0 = (aa0 > 15.f) ? aa0 : log1pf(__expf(aa0));
                float sp1 = (aa1 > 15.f) ? aa1 : log1pf(__expf(aa1));
                sgs[bb*256 + j20] = sp0 * DIFF_SCALE_F;
                sgs[bb*256 + j21] = sp1 * DIFF_SCALE_F;
            }
        }
        __syncthreads();

        // p4: drift L3 (hA->mu, N=256), K=128; theta update
        {
            f32x4 m0=z4,m1=z4,m2=z4,m3=z4;
#pragma unroll
            for (int ks = 0; ks < 4; ks += 2) {
                short8 h0f = AFRAG(hA, 256, ks), h1f = AFRAG(hA, 256, ks+1);
                m0 = MFMA16(h0f, BFRAG(W3d, j20, 128, ks),   m0);
                m1 = MFMA16(h1f, BFRAG(W3d, j20, 128, ks+1), m1);
                m2 = MFMA16(h0f, BFRAG(W3d, j21, 128, ks),   m2);
                m3 = MFMA16(h1f, BFRAG(W3d, j21, 128, ks+1), m3);
            }
#pragma unroll
            for (int r = 0; r < 4; ++r) {
                int bb = l4*4 + r;
                {
                    float mu = m0[r] + m1[r] + bd3t0;
                    float dw = dW[((size_t)(b0 + bb)*5 + k)*256 + j20];
                    th[bb*256 + j20] = wrapf(th[bb*256 + j20] + mu*DT_F + sgs[bb*256 + j20]*dw);
                }
                {
                    float mu = m2[r] + m3[r] + bd3t1;
                    float dw = dW[((size_t)(b0 + bb)*5 + k)*256 + j21];
                    th[bb*256 + j21] = wrapf(th[bb*256 + j21] + mu*DT_F + sgs[bb*256 + j21]*dw);
                }
            }
        }
        __syncthreads();
    }

#pragma unroll
    for (int e = 0; e < 8; ++e) {
        int idx = tid + e*512;
        out[(size_t)b0*256 + idx] = th[idx];
    }
}

extern "C" void kernel_launch(void* const* d_in, const int* in_sizes, int n_in,
                              void* d_out, int out_size, void* d_ws, size_t ws_size,
                              hipStream_t stream) {
    const float* ctx_ang = (const float*)d_in[0];
    const float* dW      = (const float*)d_in[1];
    const float* wih     = (const float*)d_in[2];
    const float* whh     = (const float*)d_in[3];
    const float* gru_b   = (const float*)d_in[4];
    const float* gru_bn  = (const float*)d_in[5];
    const float* proj_w  = (const float*)d_in[6];
    const float* proj_b  = (const float*)d_in[7];
    const float* dr_w0   = (const float*)d_in[8];
    const float* dr_b0   = (const float*)d_in[9];
    const float* dr_w1   = (const float*)d_in[10];
    const float* dr_b1   = (const float*)d_in[11];
    const float* dr_w2   = (const float*)d_in[12];
    const float* dr_b2   = (const float*)d_in[13];
    const float* dr_w3   = (const float*)d_in[14];
    const float* dr_b3   = (const float*)d_in[15];
    const float* df_w0   = (const float*)d_in[16];
    const float* df_b0   = (const float*)d_in[17];
    const float* df_w1   = (const float*)d_in[18];
    const float* df_b1   = (const float*)d_in[19];
    const float* df_w2   = (const float*)d_in[20];
    const float* df_b2   = (const float*)d_in[21];
    float* out = (float*)d_out;

    char* ws = (char*)d_ws;
    unsigned int*   P01  = (unsigned int*)ws;                         // 134,217,728 B
    unsigned short* P2   = (unsigned short*)(ws + 134217728);         //  67,108,864 B
    unsigned short* wihb = (unsigned short*)(ws + 201326592);         //     393,216 B
    unsigned short* whhb = (unsigned short*)(ws + 201719808);         //      98,304 B
    float*          h_ws = (float*)(ws + 201818112);                  //     524,288 B

    // SDE bf16 weights live in the P01 region (dead after scan_kernel);
    // prep2 is launched AFTER scan_kernel so stream order guarantees safety.
    unsigned short* Wb  = (unsigned short*)ws;
    unsigned short* W0d = Wb;            // 73728
    unsigned short* W1d = Wb + 73728;    // 16384
    unsigned short* W2d = Wb + 90112;    // 16384
    unsigned short* W3d = Wb + 106496;   // 32768
    unsigned short* W0f = Wb + 139264;   // 73728
    unsigned short* W1f = Wb + 212992;   // 16384
    unsigned short* W2f = Wb + 229376;   // 32768

    prep_kernel<<<768, 256, 0, stream>>>(wih, whh, wihb, whhb);
    gi_gemm_kernel<<<2048, 512, 0, stream>>>(ctx_ang, wihb, P01, P2);
    scan_kernel<<<512, 512, 0, stream>>>(P01, P2, whhb, gru_b, gru_bn, h_ws);
    prep2_kernel<<<1024, 256, 0, stream>>>(dr_w0, dr_w1, dr_w2, dr_w3, df_w0, df_w1, df_w2, Wb);
    sde_kernel<<<64, 512, 0, stream>>>(ctx_ang, dW,
        proj_w, proj_b, dr_b0, dr_b1, dr_b2, dr_b3, df_b0, df_b1, df_b2,
        W0d, W1d, W2d, W3d, W0f, W1f, W2f, h_ws, out);
}